// Round 9
// baseline (175.764 us; speedup 1.0000x reference)
//
#include <hip/hip_runtime.h>

// LocallyConnected2d: B=16, C=4, H=W=128, K=7, PAD=3, fp32.
// out[b,o,h,w] = mask * sum_{i,t} xpad[b,i,h+dy,w+dx] * wn[o,i,h,w,t]
// cw = weight + 1 at center tap (t=24) for ALL (o,i); wn = |cw|/sum_t|cw|.
//
// R9 (fused7): fixes fused5's chip-wide stage/compute phase alternation
// (867 GB/s, 6 waves/CU). 256-thr blocks: 4 waves, wave wv owns i=wv;
// in-block reduction over i reuses the weight LDS (no atomics, no extra LDS).
//  - 26.6 KB LDS -> 6 blocks/CU = 24 waves/CU resident, phases de-synced.
//  - stage: 1568 f4 over 256 thr, coalesced; each weight byte read from HBM
//    exactly once chip-wide; scatter into 52-padded rows.
//  - compute reads: ds_read_b128, pos-stride 52 -> all 32 banks, conflict-free;
//    x as linear 512B/wave fvec2 from L2-hot xTp; normalize fused (1/s fold).
//  - epilogue: partials -> LDS (9-stride pad, conflict-free), sum 4 waves,
//    mask, direct store (each output written once).

typedef float fvec4 __attribute__((ext_vector_type(4)));
typedef float fvec2 __attribute__((ext_vector_type(2)));

#define HW 128
#define PW 134
#define NC 4
#define KK 49
#define WC 8                          // w-stripe per block
#define RP 52                         // padded tap-row (16B-aligned b128)
#define XTP_FLOATS (NC * PW * PW * 16)

// ---------------- prep: padded transpose x[b][i][h][w] -> xTp[i][hp][wp][b]
__global__ __launch_bounds__(256) void lc2d_prep(const float* __restrict__ x,
                                                 float* __restrict__ xTp) {
  int idx = blockIdx.x * 256 + threadIdx.x;
  if (idx >= NC * PW * PW) return;
  int wp = idx % PW;
  int r  = idx / PW;
  int hp = r % PW;
  int i  = r / PW;
  int h = hp - 3, w = wp - 3;
  bool in = (h >= 0) & (h < HW) & (w >= 0) & (w < HW);
  float v[16];
#pragma unroll
  for (int b = 0; b < 16; ++b)
    v[b] = in ? x[((b * NC + i) * HW + h) * HW + w] : 0.0f;
  float4* dst = (float4*)(xTp + (size_t)idx * 16);
  dst[0] = make_float4(v[0],  v[1],  v[2],  v[3]);
  dst[1] = make_float4(v[4],  v[5],  v[6],  v[7]);
  dst[2] = make_float4(v[8],  v[9],  v[10], v[11]);
  dst[3] = make_float4(v[12], v[13], v[14], v[15]);
}

// ---------------- fused7: block=(wc,h) 256 thr; wave wv = channel i
__global__ __launch_bounds__(256, 4)
void lc2d_fused7(const float* __restrict__ weight,
                 const float* __restrict__ xTp,
                 float* __restrict__ out) {
  __shared__ __align__(16) float Wl[16][WC][RP];   // 26.6 KB (reused for Red)

  const int tid  = threadIdx.x;
  const int wv   = tid >> 6;         // wave id = i channel (compute phase)
  const int lane = tid & 63;
  const int pos  = lane >> 3;        // 0..7 w within stripe
  const int bp   = lane & 7;         // b-pair (lane-fastest -> linear x)
  const int bid  = blockIdx.x;
  const int wc   = bid >> 7;         // 0..15
  const int h    = bid & 127;
  const int w0   = wc * WC;

  // ---- stage 16 panels (1568 f4) across all 256 threads, coalesced ----
  // base (h*128+w0)*49 = 392*(16h+wc) ≡ 0 mod 4 -> f4-aligned ✓
  const float* wb = weight + (size_t)(h * HW + w0) * KK;
#pragma unroll
  for (int k = 0; k < 7; ++k) {
    int f = tid + k * 256;
    if (f < 1568) {
      int oi = f / 98;               // panel (o*4+i)
      int fl = f - oi * 98;
      fvec4 v = *(const fvec4*)(wb + (size_t)oi * 802816 + 4 * fl);
      int e = 4 * fl;
#pragma unroll
      for (int j = 0; j < 4; ++j) {
        int ee = e + j;
        int p  = ee / 49;
        int t  = ee - p * 49;
        Wl[oi][p][t] = v[j];
      }
    }
  }
  __syncthreads();

  // ---- compute: this wave's i = wv ----
  const int i = wv;
  const float* xb = xTp + ((size_t)(i * PW + h) * PW + (w0 + pos)) * 16 + 2 * bp;

  float s0 = 0.f, s1 = 0.f, s2 = 0.f, s3 = 0.f;
  fvec2 t0 = {0.f, 0.f}, t1 = t0, t2 = t0, t3 = t0;

#pragma unroll
  for (int tg = 0; tg < 12; ++tg) {              // taps 0..47
    fvec4 q0 = *(const fvec4*)&Wl[0 * 4 + i][pos][tg * 4];
    fvec4 q1 = *(const fvec4*)&Wl[1 * 4 + i][pos][tg * 4];
    fvec4 q2 = *(const fvec4*)&Wl[2 * 4 + i][pos][tg * 4];
    fvec4 q3 = *(const fvec4*)&Wl[3 * 4 + i][pos][tg * 4];
#pragma unroll
    for (int j = 0; j < 4; ++j) {
      const int t  = tg * 4 + j;
      const int dy = t / 7, dx = t - dy * 7;
      fvec2 xv = *(const fvec2*)(xb + (dy * PW + dx) * 16);  // linear 512B/wave
      float a0 = q0[j], a1 = q1[j], a2 = q2[j], a3 = q3[j];
      if (t == 24) { a0 += 1.f; a1 += 1.f; a2 += 1.f; a3 += 1.f; }
      a0 = fabsf(a0); a1 = fabsf(a1); a2 = fabsf(a2); a3 = fabsf(a3);
      s0 += a0; s1 += a1; s2 += a2; s3 += a3;
      t0 += xv * a0; t1 += xv * a1; t2 += xv * a2; t3 += xv * a3;
    }
  }
  {                                              // tap t=48 (dy=6,dx=6)
    fvec2 xv = *(const fvec2*)(xb + (6 * PW + 6) * 16);
    float a0 = fabsf(Wl[0 * 4 + i][pos][48]);
    float a1 = fabsf(Wl[1 * 4 + i][pos][48]);
    float a2 = fabsf(Wl[2 * 4 + i][pos][48]);
    float a3 = fabsf(Wl[3 * 4 + i][pos][48]);
    s0 += a0; s1 += a1; s2 += a2; s3 += a3;
    t0 += xv * a0; t1 += xv * a1; t2 += xv * a2; t3 += xv * a3;
  }
  // fold this (o,i,h,w)-row's L1 scale
  t0 *= (1.f / s0); t1 *= (1.f / s1); t2 *= (1.f / s2); t3 *= (1.f / s3);

  // ---- in-block i-reduction: partials into (reused) LDS ----
  __syncthreads();                               // all waves done reading Wl
  float* Red = (float*)Wl;                       // [4][64][9] = 9.2 KB
  float* rp = Red + (wv * 64 + lane) * 9;        // stride 9: conflict-free
  rp[0] = t0[0]; rp[1] = t0[1]; rp[2] = t1[0]; rp[3] = t1[1];
  rp[4] = t2[0]; rp[5] = t2[1]; rp[6] = t3[0]; rp[7] = t3[1];
  __syncthreads();

  // ---- epilogue: thread = (o=tid>>6, pos, bp); sum 4 waves, mask, store ----
  const int o = wv;
  float r0 = 0.f, r1 = 0.f;
#pragma unroll
  for (int k = 0; k < 4; ++k) {
    const float* q = Red + (k * 64 + lane) * 9 + o * 2;
    r0 += q[0];
    r1 += q[1];
  }
  fvec2 m = *(const fvec2*)(xTp +
      ((size_t)(o * PW + h + 3) * PW + (w0 + pos + 3)) * 16 + 2 * bp);
  const size_t ob = (size_t)h * HW + w0 + pos;
  out[(size_t)((2 * bp + 0) * NC + o) * 16384 + ob] = (m[0] != 0.f) ? r0 : 0.f;
  out[(size_t)((2 * bp + 1) * NC + o) * 16384 + ob] = (m[1] != 0.f) ? r1 : 0.f;
}

// ---------------- fallback (no-ws): direct x, i-split blocks + atomics
__global__ __launch_bounds__(256) void lc2d_nows(const float* __restrict__ weight,
                                                 const float* __restrict__ x,
                                                 float* __restrict__ out) {
  __shared__ __align__(16) float Raw[NC * 784];
  const int tid = threadIdx.x;
  const int bid = blockIdx.x;
  const int i   = bid >> 10;
  const int r2  = bid & 1023;
  const int h   = r2 >> 3;
  const int wcc = r2 & 7;
  const int w0  = wcc * 16;
  const size_t wbase = (size_t)i * 802816 + (size_t)(h * HW + w0) * KK;
#pragma unroll
  for (int k = 0; k < 4; ++k) {
    int f = tid + k * 256;
    if (f < 784) {
      int o = f / 196, g = f - o * 196;
      *(float4*)(&Raw[o * 784 + 4 * g]) =
          *(const float4*)(weight + wbase + (size_t)o * 3211264 + 4 * g);
    }
  }
  __syncthreads();
  {
    const int r = tid >> 2, q = tid & 3;
    const int rowb = (r >> 4) * 784 + (r & 15) * KK;
    const int t0 = q * 12;
    float v[13];
#pragma unroll
    for (int j = 0; j < 12; ++j) v[j] = Raw[rowb + t0 + j];
    v[12] = (q == 3) ? Raw[rowb + 48] : 0.f;
    float s = 0.f;
#pragma unroll
    for (int j = 0; j < 13; ++j) s += fabsf(v[j]);
    if (q == 2) s += fabsf(v[0] + 1.f) - fabsf(v[0]);
    s += __shfl_xor(s, 1);
    s += __shfl_xor(s, 2);
    const float inv = 1.f / s;
    if (q == 2) v[0] += 1.f;
#pragma unroll
    for (int j = 0; j < 12; ++j) Raw[rowb + t0 + j] = fabsf(v[j]) * inv;
    if (q == 3) Raw[rowb + 48] = fabsf(v[12]) * inv;
  }
  __syncthreads();
  const int b = tid & 15, pos = tid >> 4, w = w0 + pos;
  float acc[NC] = {0.f, 0.f, 0.f, 0.f};
  float xv[7];
#pragma unroll
  for (int dy = 0; dy < 7; ++dy) {
    int hh = h + dy - 3;
    bool hin = (hh >= 0) & (hh < HW);
#pragma unroll
    for (int dx = 0; dx < 7; ++dx) {
      int ww = w + dx - 3;
      bool in = hin & (ww >= 0) & (ww < HW);
      xv[dx] = in ? x[((b * NC + i) * HW + hh) * HW + ww] : 0.f;
    }
#pragma unroll
    for (int o = 0; o < NC; ++o) {
      const float* wr = &Raw[o * 784 + pos * KK + dy * 7];
#pragma unroll
      for (int dx = 0; dx < 7; ++dx) acc[o] = fmaf(xv[dx], wr[dx], acc[o]);
    }
  }
#pragma unroll
  for (int o = 0; o < NC; ++o) {
    float xc = x[((b * NC + o) * HW + h) * HW + w];
    atomicAdd(&out[((b * NC + o) * HW + h) * HW + w], (xc != 0.f) ? acc[o] : 0.f);
  }
}

extern "C" void kernel_launch(void* const* d_in, const int* in_sizes, int n_in,
                              void* d_out, int out_size, void* d_ws, size_t ws_size,
                              hipStream_t stream) {
  const float* x      = (const float*)d_in[0];   // (16,4,128,128) fp32
  const float* weight = (const float*)d_in[1];   // (1,4,4,128,128,49) fp32
  float* out = (float*)d_out;                    // (16,4,128,128) fp32

  const size_t xtp_bytes = (size_t)XTP_FLOATS * 4;   // 4.6 MB
  if (ws_size >= xtp_bytes) {
    float* xTp = (float*)d_ws;
    lc2d_prep<<<(NC * PW * PW + 255) / 256, 256, 0, stream>>>(x, xTp);
    lc2d_fused7<<<2048, 256, 0, stream>>>(weight, xTp, out);
  } else {
    hipMemsetAsync(d_out, 0, (size_t)out_size * sizeof(float), stream);
    lc2d_nows<<<4096, 256, 0, stream>>>(weight, x, out);
  }
}